// Round 1
// baseline (2479.207 us; speedup 1.0000x reference)
//
#include <hip/hip_runtime.h>
#include <hip/hip_bf16.h>

// SparseFactorisationDense: out = relu(scaling * (x @ (k0*m0) @ (k1*m1) @ (k2*m2)) + bias)
// B=8192, D=U=2048, fp32 throughout.
//
// R0 baseline: fp32 VALU tiled GEMM x3 (no fp32 MFMA exists on CDNA4).
// 128x128 tile, BK=16, 256 threads, 8x8 acc per thread.
// Mask multiply fused into B staging; scale+bias+relu fused into GEMM3.
// Ping-pong: x -> d_out -> d_ws -> d_out  (ws needs 64 MiB only).

#define BM 128
#define BN 128
#define BK 16
#define TM 8
#define TN 8
#define LDA_S (BM + 4)   // +4 floats keeps 16B alignment and staggers banks
#define LDB_S (BN + 4)

template<int EPI>
__global__ __launch_bounds__(256)
void gemm_masked_f32(const float* __restrict__ A,
                     const float* __restrict__ Kw,
                     const float* __restrict__ Mw,
                     float* __restrict__ C,
                     const float* __restrict__ scaling,
                     const float* __restrict__ bias,
                     int Ndim, int Kdim)
{
    __shared__ float As[BK * LDA_S];   // As[k][m], transposed A tile
    __shared__ float Bs[BK * LDB_S];   // Bs[k][n]

    const int tid = threadIdx.x;
    const int tx = tid & 15;   // -> N
    const int ty = tid >> 4;   // -> M
    const int bn = blockIdx.x * BN;
    const int bm = blockIdx.y * BM;

    float acc[TM][TN];
#pragma unroll
    for (int i = 0; i < TM; ++i)
#pragma unroll
        for (int j = 0; j < TN; ++j) acc[i][j] = 0.f;

    const float* Ab = A + (size_t)bm * Kdim;

    for (int k0 = 0; k0 < Kdim; k0 += BK) {
        // ---- stage A tile: 128 rows x 16 k (512 float4 slots, 2 per thread)
#pragma unroll
        for (int s = tid; s < (BM * BK) / 4; s += 256) {
            const int row = s >> 2;
            const int kq  = (s & 3) << 2;
            const float4 av = *reinterpret_cast<const float4*>(
                Ab + (size_t)row * Kdim + k0 + kq);
            As[(kq + 0) * LDA_S + row] = av.x;
            As[(kq + 1) * LDA_S + row] = av.y;
            As[(kq + 2) * LDA_S + row] = av.z;
            As[(kq + 3) * LDA_S + row] = av.w;
        }
        // ---- stage B tile: 16 k x 128 n, mask fused (w = k*m on the fly)
#pragma unroll
        for (int s = tid; s < (BK * BN) / 4; s += 256) {
            const int row = s >> 5;
            const int nq  = (s & 31) << 2;
            const size_t g = (size_t)(k0 + row) * Ndim + bn + nq;
            float4 kv = *reinterpret_cast<const float4*>(Kw + g);
            const float4 mv = *reinterpret_cast<const float4*>(Mw + g);
            kv.x *= mv.x; kv.y *= mv.y; kv.z *= mv.z; kv.w *= mv.w;
            *reinterpret_cast<float4*>(&Bs[row * LDB_S + nq]) = kv;
        }
        __syncthreads();

        // ---- compute: 16 k-steps x (8x8 outer product)
#pragma unroll
        for (int kk = 0; kk < BK; ++kk) {
            const float4 a0 = *reinterpret_cast<const float4*>(&As[kk * LDA_S + ty * TM]);
            const float4 a1 = *reinterpret_cast<const float4*>(&As[kk * LDA_S + ty * TM + 4]);
            const float4 b0 = *reinterpret_cast<const float4*>(&Bs[kk * LDB_S + tx * TN]);
            const float4 b1 = *reinterpret_cast<const float4*>(&Bs[kk * LDB_S + tx * TN + 4]);
            const float a[TM] = {a0.x, a0.y, a0.z, a0.w, a1.x, a1.y, a1.z, a1.w};
            const float b[TN] = {b0.x, b0.y, b0.z, b0.w, b1.x, b1.y, b1.z, b1.w};
#pragma unroll
            for (int i = 0; i < TM; ++i)
#pragma unroll
                for (int j = 0; j < TN; ++j)
                    acc[i][j] = fmaf(a[i], b[j], acc[i][j]);
        }
        __syncthreads();
    }

    // ---- epilogue + store (float4)
    const float sc = EPI ? scaling[0] : 0.f;
#pragma unroll
    for (int i = 0; i < TM; ++i) {
        const size_t row = (size_t)(bm + ty * TM + i);
        float* crow = C + row * Ndim + bn + tx * TN;
#pragma unroll
        for (int jq = 0; jq < TN; jq += 4) {
            float4 v = {acc[i][jq], acc[i][jq + 1], acc[i][jq + 2], acc[i][jq + 3]};
            if (EPI) {
                const float4 bv = *reinterpret_cast<const float4*>(bias + bn + tx * TN + jq);
                v.x = fmaxf(fmaf(sc, v.x, bv.x), 0.f);
                v.y = fmaxf(fmaf(sc, v.y, bv.y), 0.f);
                v.z = fmaxf(fmaf(sc, v.z, bv.z), 0.f);
                v.w = fmaxf(fmaf(sc, v.w, bv.w), 0.f);
            }
            *reinterpret_cast<float4*>(crow + jq) = v;
        }
    }
}

extern "C" void kernel_launch(void* const* d_in, const int* in_sizes, int n_in,
                              void* d_out, int out_size, void* d_ws, size_t ws_size,
                              hipStream_t stream)
{
    // setup_inputs order: x, k0, k1, k2, m0, m1, m2, scaling, bias
    const float* x    = (const float*)d_in[0];
    const float* k0   = (const float*)d_in[1];
    const float* k1   = (const float*)d_in[2];
    const float* k2   = (const float*)d_in[3];
    const float* m0   = (const float*)d_in[4];
    const float* m1   = (const float*)d_in[5];
    const float* m2   = (const float*)d_in[6];
    const float* sc   = (const float*)d_in[7];
    const float* bias = (const float*)d_in[8];

    const int Kdim = 2048;                 // D = U = 2048
    const int Ndim = 2048;
    const int Mdim = in_sizes[0] / Kdim;   // 8192

    float* out = (float*)d_out;            // also used as ping buffer
    float* t   = (float*)d_ws;             // 8192*2048 floats = 64 MiB scratch

    dim3 grid(Ndim / BN, Mdim / BM);       // (16, 64)
    dim3 block(256);

    // L1: out1 = x @ (k0*m0)            -> d_out
    gemm_masked_f32<0><<<grid, block, 0, stream>>>(x,   k0, m0, out, nullptr, nullptr, Ndim, Kdim);
    // L2: out2 = out1 @ (k1*m1)         -> ws
    gemm_masked_f32<0><<<grid, block, 0, stream>>>(out, k1, m1, t,   nullptr, nullptr, Ndim, Kdim);
    // L3: out = relu(sc * (out2 @ (k2*m2)) + bias) -> d_out
    gemm_masked_f32<1><<<grid, block, 0, stream>>>(t,   k2, m2, out, sc, bias, Ndim, Kdim);
}

// Round 2
// 422.812 us; speedup vs baseline: 5.8636x; 5.8636x over previous
//
#include <hip/hip_runtime.h>
#include <hip/hip_bf16.h>

// SparseFactorisationDense: out = relu(scaling * (x @ (k0*m0) @ (k1*m1) @ (k2*m2)) + bias)
// B=8192, D=U=2048. R2: bf16 MFMA path.
//   convT: wbT[n][k] = bf16(k[k][n]*m[k][n])   (transposed masked weights, bf16)
//   gemm : 128x128 tile, BK=32, 4 waves, mfma_f32_16x16x32_bf16, fp32 accum.
// Chain: x(f32) -> act1(bf16, in d_out) -> act2(bf16, in ws) -> out(f32, d_out).

typedef __attribute__((ext_vector_type(8))) short  short8;
typedef __attribute__((ext_vector_type(8))) ushort ushort8v;
typedef __attribute__((ext_vector_type(4))) float  f32x4;

#define BM 128
#define BN 128
#define BK 32
#define LDSW 40   // 32 k-elems + 8 pad (ushorts) = 80B rows: 16B-aligned, bank-staggered
#define KD 2048
#define ND 2048

__device__ __forceinline__ ushort f2b(float f) {      // fp32 -> bf16 RNE
    union { float f; unsigned u; } v; v.f = f;
    unsigned r = v.u + 0x7fffu + ((v.u >> 16) & 1u);
    return (ushort)(r >> 16);
}

// ---- masked-weight transpose+convert: wbT[n][k] = bf16(kw[k][n]*mw[k][n])
__global__ __launch_bounds__(256)
void convT(const float* __restrict__ kw, const float* __restrict__ mw,
           ushort* __restrict__ wbT)
{
    __shared__ ushort t[32][36];
    const int tid = threadIdx.x;
    const int bk = blockIdx.x * 32, bn = blockIdx.y * 32;
    {
        const int r = tid >> 3, c = (tid & 7) * 4;
        const size_t g = (size_t)(bk + r) * ND + bn + c;
        const float4 kv = *reinterpret_cast<const float4*>(kw + g);
        const float4 mv = *reinterpret_cast<const float4*>(mw + g);
        t[r][c + 0] = f2b(kv.x * mv.x);
        t[r][c + 1] = f2b(kv.y * mv.y);
        t[r][c + 2] = f2b(kv.z * mv.z);
        t[r][c + 3] = f2b(kv.w * mv.w);
    }
    __syncthreads();
    {
        const int n = tid >> 3, kq = (tid & 7) * 4;
        ushort4 o;
        o.x = t[kq + 0][n]; o.y = t[kq + 1][n];
        o.z = t[kq + 2][n]; o.w = t[kq + 3][n];
        *reinterpret_cast<ushort4*>(&wbT[(size_t)(bn + n) * KD + bk + kq]) = o;
    }
}

// ---- bf16 MFMA GEMM: C[M][N] = A[M][K] @ B[K][N], B given as BT[n][k] bf16.
// AFP32: A is fp32 (convert during staging) else bf16.
// EPI:   1 -> C fp32 with relu(sc*v + bias); 0 -> C bf16.
template<int AFP32, int EPI>
__global__ __launch_bounds__(256)
void gemm_bf16(const void* __restrict__ Ain, const ushort* __restrict__ BT,
               void* __restrict__ Cout,
               const float* __restrict__ scaling, const float* __restrict__ bias)
{
    __shared__ __align__(16) ushort As[BM * LDSW];
    __shared__ __align__(16) ushort Bs[BN * LDSW];

    const int tid  = threadIdx.x;
    const int lane = tid & 63;
    const int wid  = tid >> 6;
    const int wr   = wid >> 1, wc = wid & 1;       // 2x2 wave grid, 64x64 each
    const int l15  = lane & 15;
    const int kq   = lane >> 4;                    // k-group 0..3
    const int bn   = blockIdx.x * BN;
    const int bm   = blockIdx.y * BM;

    const int srow = tid >> 1;                     // staging: 2 threads/row
    const int sh16 = (tid & 1) * 16;               // which 16-elem k-half

    f32x4 acc[4][4] = {};

    for (int k0 = 0; k0 < KD; k0 += BK) {
        // ---- stage A tile (rows bm.., k0..k0+32)
        if constexpr (AFP32) {
            const float* a = (const float*)Ain + (size_t)(bm + srow) * KD + k0 + sh16;
            const float4 f0 = reinterpret_cast<const float4*>(a)[0];
            const float4 f1 = reinterpret_cast<const float4*>(a)[1];
            const float4 f2 = reinterpret_cast<const float4*>(a)[2];
            const float4 f3 = reinterpret_cast<const float4*>(a)[3];
            ushort8v u0, u1;
            u0[0]=f2b(f0.x); u0[1]=f2b(f0.y); u0[2]=f2b(f0.z); u0[3]=f2b(f0.w);
            u0[4]=f2b(f1.x); u0[5]=f2b(f1.y); u0[6]=f2b(f1.z); u0[7]=f2b(f1.w);
            u1[0]=f2b(f2.x); u1[1]=f2b(f2.y); u1[2]=f2b(f2.z); u1[3]=f2b(f2.w);
            u1[4]=f2b(f3.x); u1[5]=f2b(f3.y); u1[6]=f2b(f3.z); u1[7]=f2b(f3.w);
            *reinterpret_cast<ushort8v*>(&As[srow * LDSW + sh16])     = u0;
            *reinterpret_cast<ushort8v*>(&As[srow * LDSW + sh16 + 8]) = u1;
        } else {
            const ushort* a = (const ushort*)Ain + (size_t)(bm + srow) * KD + k0 + sh16;
            const ushort8v u0 = reinterpret_cast<const ushort8v*>(a)[0];
            const ushort8v u1 = reinterpret_cast<const ushort8v*>(a)[1];
            *reinterpret_cast<ushort8v*>(&As[srow * LDSW + sh16])     = u0;
            *reinterpret_cast<ushort8v*>(&As[srow * LDSW + sh16 + 8]) = u1;
        }
        // ---- stage B tile from BT[n][k] (rows bn.., k0..k0+32)
        {
            const ushort* b = BT + (size_t)(bn + srow) * KD + k0 + sh16;
            const ushort8v u0 = reinterpret_cast<const ushort8v*>(b)[0];
            const ushort8v u1 = reinterpret_cast<const ushort8v*>(b)[1];
            *reinterpret_cast<ushort8v*>(&Bs[srow * LDSW + sh16])     = u0;
            *reinterpret_cast<ushort8v*>(&Bs[srow * LDSW + sh16 + 8]) = u1;
        }
        __syncthreads();

        // ---- compute: 4x4 fragments of 16x16, K=32 per MFMA
        short8 af[4], bfr[4];
#pragma unroll
        for (int m = 0; m < 4; ++m)
            af[m] = *reinterpret_cast<const short8*>(
                &As[(wr * 64 + m * 16 + l15) * LDSW + kq * 8]);
#pragma unroll
        for (int n = 0; n < 4; ++n)
            bfr[n] = *reinterpret_cast<const short8*>(
                &Bs[(wc * 64 + n * 16 + l15) * LDSW + kq * 8]);
#pragma unroll
        for (int m = 0; m < 4; ++m)
#pragma unroll
            for (int n = 0; n < 4; ++n)
                acc[m][n] = __builtin_amdgcn_mfma_f32_16x16x32_bf16(
                    af[m], bfr[n], acc[m][n], 0, 0, 0);
        __syncthreads();
    }

    // ---- epilogue: D[(lane>>4)*4 + r][lane&15] per fragment (m89 layout)
    const float sc = EPI ? scaling[0] : 0.f;
#pragma unroll
    for (int m = 0; m < 4; ++m) {
        const int grow0 = bm + wr * 64 + m * 16 + kq * 4;
#pragma unroll
        for (int n = 0; n < 4; ++n) {
            const int gcol = bn + wc * 64 + n * 16 + l15;
            if constexpr (EPI) {
                const float bv = bias[gcol];
                float* o = (float*)Cout;
#pragma unroll
                for (int r = 0; r < 4; ++r)
                    o[(size_t)(grow0 + r) * ND + gcol] =
                        fmaxf(fmaf(sc, acc[m][n][r], bv), 0.f);
            } else {
                ushort* o = (ushort*)Cout;
#pragma unroll
                for (int r = 0; r < 4; ++r)
                    o[(size_t)(grow0 + r) * ND + gcol] = f2b(acc[m][n][r]);
            }
        }
    }
}

extern "C" void kernel_launch(void* const* d_in, const int* in_sizes, int n_in,
                              void* d_out, int out_size, void* d_ws, size_t ws_size,
                              hipStream_t stream)
{
    // inputs: x, k0, k1, k2, m0, m1, m2, scaling, bias
    const float* x    = (const float*)d_in[0];
    const float* k0w  = (const float*)d_in[1];
    const float* k1w  = (const float*)d_in[2];
    const float* k2w  = (const float*)d_in[3];
    const float* m0w  = (const float*)d_in[4];
    const float* m1w  = (const float*)d_in[5];
    const float* m2w  = (const float*)d_in[6];
    const float* sc   = (const float*)d_in[7];
    const float* bias = (const float*)d_in[8];

    const int Md = in_sizes[0] / KD;               // 8192

    ushort* act1 = (ushort*)d_out;                 // 32MB bf16 in d_out (dead before GEMM3 writes)
    ushort* act2 = (ushort*)d_ws;                  // 32MB bf16
    ushort* wbT  = (ushort*)d_ws + (size_t)Md * KD; // 8MB bf16, reused per layer
    float*  out  = (float*)d_out;

    dim3 gT(KD / 32, ND / 32), bT(256);            // (64,64)
    dim3 gG(ND / BN, Md / BM), bG(256);            // (16,64)

    // layer 1: act1 = bf16(x @ (k0*m0))
    convT<<<gT, bT, 0, stream>>>(k0w, m0w, wbT);
    gemm_bf16<1, 0><<<gG, bG, 0, stream>>>(x, wbT, act1, nullptr, nullptr);
    // layer 2: act2 = bf16(act1 @ (k1*m1))
    convT<<<gT, bT, 0, stream>>>(k1w, m1w, wbT);
    gemm_bf16<0, 0><<<gG, bG, 0, stream>>>(act1, wbT, act2, nullptr, nullptr);
    // layer 3: out = relu(sc * (act2 @ (k2*m2)) + bias)
    convT<<<gT, bT, 0, stream>>>(k2w, m2w, wbT);
    gemm_bf16<0, 1><<<gG, bG, 0, stream>>>(act2, wbT, out, sc, bias);
}

// Round 4
// 333.602 us; speedup vs baseline: 7.4316x; 1.2674x over previous
//
#include <hip/hip_runtime.h>
#include <hip/hip_bf16.h>

// SparseFactorisationDense: out = relu(scaling * (x @ (k0*m0) @ (k1*m1) @ (k2*m2)) + bias)
// B=8192, D=U=2048.
// R4 = R3 resubmit (container died before measurement; kernel re-audited, no
// hang source found).
// R3: m97-structure GEMM — global_load_lds width-16 staging, linear LDS,
//     slot-XOR swizzle on (source, ds_read) pair, 128x128 tile, BK=32,
//     4 waves x (64x64), mfma_f32_16x16x32_bf16.
// Pipeline: convx (x->bf16, in d_out upper half), convT3 (3 masked transposed
// bf16 weight mats, in ws), then 3 GEMMs. Epilogue fused into GEMM3.

typedef __attribute__((ext_vector_type(8))) short  short8;
typedef __attribute__((ext_vector_type(8))) ushort ushort8v;
typedef __attribute__((ext_vector_type(4))) float  f32x4;

#define KD 2048
#define ND 2048
#define BM 128
#define BN 128
#define BK 32

__device__ __forceinline__ ushort f2b(float f) {      // fp32 -> bf16 RNE
    union { float f; unsigned u; } v; v.f = f;
    unsigned r = v.u + 0x7fffu + ((v.u >> 16) & 1u);
    return (ushort)(r >> 16);
}

__device__ __forceinline__ void gload16(const void* g, void* l) {
    __builtin_amdgcn_global_load_lds(
        (const __attribute__((address_space(1))) void*)g,
        (__attribute__((address_space(3))) void*)l, 16, 0, 0);
}

// ---- x: fp32 -> bf16, 8 elems/thread
__global__ __launch_bounds__(256)
void convx(const float* __restrict__ x, ushort* __restrict__ xb)
{
    const size_t i = (size_t)blockIdx.x * 256 + threadIdx.x;
    const float4* src = reinterpret_cast<const float4*>(x) + i * 2;
    const float4 f0 = src[0], f1 = src[1];
    ushort8v u;
    u[0]=f2b(f0.x); u[1]=f2b(f0.y); u[2]=f2b(f0.z); u[3]=f2b(f0.w);
    u[4]=f2b(f1.x); u[5]=f2b(f1.y); u[6]=f2b(f1.z); u[7]=f2b(f1.w);
    reinterpret_cast<ushort8v*>(xb)[i] = u;
}

// ---- masked-weight transpose+convert for all 3 layers (blockIdx.z picks layer)
__global__ __launch_bounds__(256)
void convT3(const float* __restrict__ k0w, const float* __restrict__ k1w,
            const float* __restrict__ k2w, const float* __restrict__ m0w,
            const float* __restrict__ m1w, const float* __restrict__ m2w,
            ushort* __restrict__ wbT)
{
    const int z = blockIdx.z;
    const float* kw = z == 0 ? k0w : (z == 1 ? k1w : k2w);
    const float* mw = z == 0 ? m0w : (z == 1 ? m1w : m2w);
    ushort* o = wbT + (size_t)z * KD * ND;

    __shared__ ushort t[32][36];
    const int tid = threadIdx.x;
    const int bk = blockIdx.x * 32, bn = blockIdx.y * 32;
    {
        const int r = tid >> 3, c = (tid & 7) * 4;
        const size_t g = (size_t)(bk + r) * ND + bn + c;
        const float4 kv = *reinterpret_cast<const float4*>(kw + g);
        const float4 mv = *reinterpret_cast<const float4*>(mw + g);
        t[r][c + 0] = f2b(kv.x * mv.x);
        t[r][c + 1] = f2b(kv.y * mv.y);
        t[r][c + 2] = f2b(kv.z * mv.z);
        t[r][c + 3] = f2b(kv.w * mv.w);
    }
    __syncthreads();
    {
        const int n = tid >> 3, kq = (tid & 7) * 4;
        ushort4 ov;
        ov.x = t[kq + 0][n]; ov.y = t[kq + 1][n];
        ov.z = t[kq + 2][n]; ov.w = t[kq + 3][n];
        *reinterpret_cast<ushort4*>(&o[(size_t)(bn + n) * KD + bk + kq]) = ov;
    }
}

// ---- bf16 MFMA GEMM (m97 structure): C[M][N] = A[M][K] @ BT[N][K]^T
// LDS linear [128][32] ushort per operand; staging via global_load_lds x16B.
// Swizzle (both-sides involution): physical 16B-slot = logical ^ ((row>>1)&3),
// applied to the global SOURCE at stage time and to the ds_read address.
template<int EPI>
__global__ __launch_bounds__(256)
void gemm_bf16(const ushort* __restrict__ A, const ushort* __restrict__ BT,
               void* __restrict__ Cout,
               const float* __restrict__ scaling, const float* __restrict__ bias)
{
    __shared__ __align__(16) ushort As[BM * BK];
    __shared__ __align__(16) ushort Bs[BN * BK];

    const int tid  = threadIdx.x;
    const int lane = tid & 63;
    const int wid  = tid >> 6;
    const int wr   = wid >> 1, wc = wid & 1;       // 2x2 wave grid, 64x64 each
    const int l15  = lane & 15;
    const int kq   = lane >> 4;
    const int bn   = blockIdx.x * BN;
    const int bm   = blockIdx.y * BM;

    const int srow  = lane >> 2;                   // row within 16-row group
    const int sslot = lane & 3;                    // physical 16B slot in row
    const int sg    = sslot ^ ((srow >> 1) & 3);   // swizzled logical slot

    f32x4 acc[4][4] = {};

    for (int k0 = 0; k0 < KD; k0 += BK) {
        // ---- stage: each wave DMAs 16 rows (1KB) per iter, 2 iters, A and B
#pragma unroll
        for (int i = 0; i < 2; ++i) {
            const int rgrp = (i * 4 + wid) * 16;   // wave-uniform row group
            const int r    = rgrp + srow;
            gload16(A  + (size_t)(bm + r) * KD + k0 + sg * 8, &As[rgrp * BK]);
            gload16(BT + (size_t)(bn + r) * KD + k0 + sg * 8, &Bs[rgrp * BK]);
        }
        __syncthreads();

        // ---- fragments (swizzled ds_read) + 16 MFMA
        short8 af[4], bf[4];
#pragma unroll
        for (int m = 0; m < 4; ++m) {
            const int r = wr * 64 + m * 16 + l15;
            af[m] = *reinterpret_cast<const short8*>(
                &As[r * BK + (kq ^ ((r >> 1) & 3)) * 8]);
        }
#pragma unroll
        for (int n = 0; n < 4; ++n) {
            const int r = wc * 64 + n * 16 + l15;
            bf[n] = *reinterpret_cast<const short8*>(
                &Bs[r * BK + (kq ^ ((r >> 1) & 3)) * 8]);
        }
#pragma unroll
        for (int m = 0; m < 4; ++m)
#pragma unroll
            for (int n = 0; n < 4; ++n)
                acc[m][n] = __builtin_amdgcn_mfma_f32_16x16x32_bf16(
                    af[m], bf[n], acc[m][n], 0, 0, 0);
        __syncthreads();
    }

    // ---- epilogue: D row = kq*4 + r, col = l15 (m89 layout)
    const float sc = EPI ? scaling[0] : 0.f;
#pragma unroll
    for (int m = 0; m < 4; ++m) {
        const int grow0 = bm + wr * 64 + m * 16 + kq * 4;
#pragma unroll
        for (int n = 0; n < 4; ++n) {
            const int gcol = bn + wc * 64 + n * 16 + l15;
            if constexpr (EPI) {
                const float bv = bias[gcol];
                float* o = (float*)Cout;
#pragma unroll
                for (int r = 0; r < 4; ++r)
                    o[(size_t)(grow0 + r) * ND + gcol] =
                        fmaxf(fmaf(sc, acc[m][n][r], bv), 0.f);
            } else {
                ushort* o = (ushort*)Cout;
#pragma unroll
                for (int r = 0; r < 4; ++r)
                    o[(size_t)(grow0 + r) * ND + gcol] = f2b(acc[m][n][r]);
            }
        }
    }
}

extern "C" void kernel_launch(void* const* d_in, const int* in_sizes, int n_in,
                              void* d_out, int out_size, void* d_ws, size_t ws_size,
                              hipStream_t stream)
{
    // inputs: x, k0, k1, k2, m0, m1, m2, scaling, bias
    const float* x    = (const float*)d_in[0];
    const float* k0w  = (const float*)d_in[1];
    const float* k1w  = (const float*)d_in[2];
    const float* k2w  = (const float*)d_in[3];
    const float* m0w  = (const float*)d_in[4];
    const float* m1w  = (const float*)d_in[5];
    const float* m2w  = (const float*)d_in[6];
    const float* sc   = (const float*)d_in[7];
    const float* bias = (const float*)d_in[8];

    const int Md = in_sizes[0] / KD;               // 8192
    const size_t NE = (size_t)Md * KD;             // 16.7M elems

    // d_out (64MB fp32): [act1 bf16 32MB][x_bf16 32MB]; GEMM3 overwrites all.
    ushort* act1 = (ushort*)d_out;
    ushort* xb   = (ushort*)d_out + NE;
    float*  out  = (float*)d_out;
    // ws: [act2 bf16 32MB][wbT0 8MB][wbT1 8MB][wbT2 8MB] = 56MB
    ushort* act2 = (ushort*)d_ws;
    ushort* wbT  = (ushort*)d_ws + NE;

    dim3 bl(256);
    dim3 gX(NE / (256 * 8));                       // 8192
    dim3 gT(KD / 32, ND / 32, 3);                  // (64,64,3)
    dim3 gG(ND / BN, Md / BM);                     // (16,64)

    convx <<<gX, bl, 0, stream>>>(x, xb);
    convT3<<<gT, bl, 0, stream>>>(k0w, k1w, k2w, m0w, m1w, m2w, wbT);

    gemm_bf16<0><<<gG, bl, 0, stream>>>(xb,   wbT,               act1, nullptr, nullptr);
    gemm_bf16<0><<<gG, bl, 0, stream>>>(act1, wbT + (size_t)KD * ND,     act2, nullptr, nullptr);
    gemm_bf16<1><<<gG, bl, 0, stream>>>(act2, wbT + (size_t)2 * KD * ND, out,  sc, bias);
}

// Round 5
// 235.057 us; speedup vs baseline: 10.5473x; 1.4192x over previous
//
#include <hip/hip_runtime.h>
#include <hip/hip_bf16.h>

// SparseFactorisationDense: out = relu(scaling * (x @ (k0*m0) @ (k1*m1) @ (k2*m2)) + bias)
// B=8192, D=U=2048.
// R5: 256x256 8-phase deep-pipelined GEMM (T3+T4+T5 per technique catalog).
//   - BK=64 as 2 K-halves of 32 (64B LDS rows -> conflict-free ds_read_b128,
//     proven 0 conflicts in R4; linear layout keeps global_load_lds legal)
//   - 512 thr / 8 waves (2Mx4N), per-wave 128x64 output, acc[8][4]
//   - LDS 128 KiB: [2 dbuf][A,B][2 kh][256*32] bf16
//   - counted vmcnt(6) gates at phases 4/8 only; raw s_barrier (no vm drain)
//   - per-phase end lgkmcnt(0): guarantees all this-phase ds_reads serviced
//     before any wave's next-phase DMA can clobber the region
// Pipeline: convx (x->bf16), convT3 (3 masked transposed bf16 weights), 3 GEMMs.

typedef __attribute__((ext_vector_type(8))) short  short8;
typedef __attribute__((ext_vector_type(8))) ushort ushort8v;
typedef __attribute__((ext_vector_type(4))) float  f32x4;

#define KD 2048
#define ND 2048

__device__ __forceinline__ ushort f2b(float f) {      // fp32 -> bf16 RNE
    union { float f; unsigned u; } v; v.f = f;
    unsigned r = v.u + 0x7fffu + ((v.u >> 16) & 1u);
    return (ushort)(r >> 16);
}

__device__ __forceinline__ void gload16(const ushort* g, ushort* l) {
    __builtin_amdgcn_global_load_lds(
        (const __attribute__((address_space(1))) void*)g,
        (__attribute__((address_space(3))) void*)l, 16, 0, 0);
}

// ---- x: fp32 -> bf16, 8 elems/thread
__global__ __launch_bounds__(256)
void convx(const float* __restrict__ x, ushort* __restrict__ xb)
{
    const size_t i = (size_t)blockIdx.x * 256 + threadIdx.x;
    const float4* src = reinterpret_cast<const float4*>(x) + i * 2;
    const float4 f0 = src[0], f1 = src[1];
    ushort8v u;
    u[0]=f2b(f0.x); u[1]=f2b(f0.y); u[2]=f2b(f0.z); u[3]=f2b(f0.w);
    u[4]=f2b(f1.x); u[5]=f2b(f1.y); u[6]=f2b(f1.z); u[7]=f2b(f1.w);
    reinterpret_cast<ushort8v*>(xb)[i] = u;
}

// ---- masked-weight transpose+convert for all 3 layers (blockIdx.z picks layer)
__global__ __launch_bounds__(256)
void convT3(const float* __restrict__ k0w, const float* __restrict__ k1w,
            const float* __restrict__ k2w, const float* __restrict__ m0w,
            const float* __restrict__ m1w, const float* __restrict__ m2w,
            ushort* __restrict__ wbT)
{
    const int z = blockIdx.z;
    const float* kw = z == 0 ? k0w : (z == 1 ? k1w : k2w);
    const float* mw = z == 0 ? m0w : (z == 1 ? m1w : m2w);
    ushort* o = wbT + (size_t)z * KD * ND;

    __shared__ ushort t[32][36];
    const int tid = threadIdx.x;
    const int bk = blockIdx.x * 32, bn = blockIdx.y * 32;
    {
        const int r = tid >> 3, c = (tid & 7) * 4;
        const size_t g = (size_t)(bk + r) * ND + bn + c;
        const float4 kv = *reinterpret_cast<const float4*>(kw + g);
        const float4 mv = *reinterpret_cast<const float4*>(mw + g);
        t[r][c + 0] = f2b(kv.x * mv.x);
        t[r][c + 1] = f2b(kv.y * mv.y);
        t[r][c + 2] = f2b(kv.z * mv.z);
        t[r][c + 3] = f2b(kv.w * mv.w);
    }
    __syncthreads();
    {
        const int n = tid >> 3, kq = (tid & 7) * 4;
        ushort4 ov;
        ov.x = t[kq + 0][n]; ov.y = t[kq + 1][n];
        ov.z = t[kq + 2][n]; ov.w = t[kq + 3][n];
        *reinterpret_cast<ushort4*>(&o[(size_t)(bn + n) * KD + bk + kq]) = ov;
    }
}

// ================= 256x256 8-phase GEMM =================
// C[M][N] = A[M][K] @ BT[N][K]^T, all bf16 in, fp32 accum.
template<int EPI>
__global__ __launch_bounds__(512, 2)
void gemm256(const ushort* __restrict__ A, const ushort* __restrict__ BT,
             void* __restrict__ Cout,
             const float* __restrict__ scaling, const float* __restrict__ bias)
{
    // [buf][op 0=A 1=B][kh][row*32 + k]  = 128 KiB
    __shared__ ushort S[2][2][2][256 * 32];

    const int tid  = threadIdx.x;
    const int lane = tid & 63;
    const int wid  = tid >> 6;                 // 0..7
    const int wr   = wid >> 2, wc = wid & 3;   // 2x4 wave grid: 128x64 per wave
    const int l15  = lane & 15;
    const int kq8  = (lane >> 4) * 8;
    const int bn   = blockIdx.x * 256;
    const int bm   = blockIdx.y * 256;
    const int srow = lane >> 2;                // staging: 16 rows / gload
    const int sk   = (lane & 3) * 8;           // k-slot within 32-k half
    const int wrow = wid * 32;                 // this wave's 32-row staging slice

    f32x4 acc[8][4] = {};

#define STAGE(op, bufl, kh, tile, G, g0) do {                                        \
    gload16(G + (size_t)((g0) + wrow + srow)      * KD + (tile)*64 + (kh)*32 + sk,   \
            &S[bufl][op][kh][(wrow)      * 32]);                                     \
    gload16(G + (size_t)((g0) + wrow + 16 + srow) * KD + (tile)*64 + (kh)*32 + sk,   \
            &S[bufl][op][kh][(wrow + 16) * 32]);                                     \
  } while (0)

#define BAR()  asm volatile("s_barrier" ::: "memory")
#define VM6()  asm volatile("s_waitcnt vmcnt(6)" ::: "memory")
#define VM0()  asm volatile("s_waitcnt vmcnt(0)" ::: "memory")
#define LGK0() asm volatile("s_waitcnt lgkmcnt(0)" ::: "memory")
#define SB()   __builtin_amdgcn_sched_barrier(0)
#define PRI1() __builtin_amdgcn_s_setprio(1)
#define PRI0() __builtin_amdgcn_s_setprio(0)

#define FA(bufl, kh, m) (*(const short8*)&S[bufl][0][kh][(wr*128 + (m)*16 + l15)*32 + kq8])
#define FB(bufl, kh, n) (*(const short8*)&S[bufl][1][kh][(wc*64  + (n)*16 + l15)*32 + kq8])

#define MM4(r, av, b0_, b1_, b2_, b3_)                                                \
    acc[r][0] = __builtin_amdgcn_mfma_f32_16x16x32_bf16(av, b0_, acc[r][0], 0, 0, 0); \
    acc[r][1] = __builtin_amdgcn_mfma_f32_16x16x32_bf16(av, b1_, acc[r][1], 0, 0, 0); \
    acc[r][2] = __builtin_amdgcn_mfma_f32_16x16x32_bf16(av, b2_, acc[r][2], 0, 0, 0); \
    acc[r][3] = __builtin_amdgcn_mfma_f32_16x16x32_bf16(av, b3_, acc[r][3], 0, 0, 0)

// One K-tile = 4 phases. Reads: P0: A-kh0[0-3]+B-kh0; P1: A-kh0[4-7]+A-kh1[0-3];
// P2: A-kh1[4-7]+B-kh1; P3: none. Stage targets (ST0..ST3) are regions whose
// last read is a strictly earlier phase (per-phase end LGK0 enforces service).
#define HALFGRP(bufl, ST0, ST1, ST2, ST3, GATE) do {                                  \
    short8 xa0 = FA(bufl,0,0), xa1 = FA(bufl,0,1), xa2 = FA(bufl,0,2), xa3 = FA(bufl,0,3); \
    short8 xb0 = FB(bufl,0,0), xb1 = FB(bufl,0,1), xb2 = FB(bufl,0,2), xb3 = FB(bufl,0,3); \
    ST0; BAR(); SB(); PRI1();                                                         \
    MM4(0, xa0, xb0, xb1, xb2, xb3); MM4(1, xa1, xb0, xb1, xb2, xb3);                 \
    MM4(2, xa2, xb0, xb1, xb2, xb3); MM4(3, xa3, xb0, xb1, xb2, xb3);                 \
    PRI0(); SB(); LGK0(); BAR();                                                      \
    short8 xa4 = FA(bufl,0,4), xa5 = FA(bufl,0,5), xa6 = FA(bufl,0,6), xa7 = FA(bufl,0,7); \
    short8 xc0 = FA(bufl,1,0), xc1 = FA(bufl,1,1), xc2 = FA(bufl,1,2), xc3 = FA(bufl,1,3); \
    ST1; BAR(); SB(); PRI1();                                                         \
    MM4(4, xa4, xb0, xb1, xb2, xb3); MM4(5, xa5, xb0, xb1, xb2, xb3);                 \
    MM4(6, xa6, xb0, xb1, xb2, xb3); MM4(7, xa7, xb0, xb1, xb2, xb3);                 \
    PRI0(); SB(); LGK0(); BAR();                                                      \
    short8 xc4 = FA(bufl,1,4), xc5 = FA(bufl,1,5), xc6 = FA(bufl,1,6), xc7 = FA(bufl,1,7); \
    short8 xd0 = FB(bufl,1,0), xd1 = FB(bufl,1,1), xd2 = FB(bufl,1,2), xd3 = FB(bufl,1,3); \
    ST2; BAR(); SB(); PRI1();                                                         \
    MM4(0, xc0, xd0, xd1, xd2, xd3); MM4(1, xc1, xd0, xd1, xd2, xd3);                 \
    MM4(2, xc2, xd0, xd1, xd2, xd3); MM4(3, xc3, xd0, xd1, xd2, xd3);                 \
    PRI0(); SB(); LGK0(); BAR();                                                      \
    ST3; GATE; BAR(); SB(); PRI1();                                                   \
    MM4(4, xc4, xd0, xd1, xd2, xd3); MM4(5, xc5, xd0, xd1, xd2, xd3);                 \
    MM4(6, xc6, xd0, xd1, xd2, xd3); MM4(7, xc7, xd0, xd1, xd2, xd3);                 \
    PRI0(); SB(); LGK0(); BAR();                                                      \
  } while (0)

    // ---- prologue: tile0 (4 half-tiles) + tile1 (B-h0, A-h0, A-h1) = 7 stages
    STAGE(0, 0, 0, 0, A,  bm); STAGE(0, 0, 1, 0, A,  bm);
    STAGE(1, 0, 0, 0, BT, bn); STAGE(1, 0, 1, 0, BT, bn);
    STAGE(1, 1, 0, 1, BT, bn); STAGE(0, 1, 0, 1, A,  bm); STAGE(0, 1, 1, 1, A,  bm);
    VM6();   // drains tile 0's 8 loads; 3 half-tiles (tile 1) stay in flight
    BAR();

    const int NITER = KD / 128;                // 16
    for (int it = 0; it < NITER - 1; ++it) {
        const int t1 = 2 * it + 1, t2 = 2 * it + 2, t3 = 2 * it + 3;
        HALFGRP(0,
                STAGE(1, 1, 1, t1, BT, bn),    // B(t1)h1  -> buf1 B-kh1 (read prev iter)
                STAGE(1, 0, 0, t2, BT, bn),    // B(t2)h0  -> buf0 B-kh0 (read P0)
                STAGE(0, 0, 0, t2, A,  bm),    // A(t2)h0  -> buf0 A-kh0 (read P0,P1)
                STAGE(0, 0, 1, t2, A,  bm),    // A(t2)h1  -> buf0 A-kh1 (read P1,P2)
                VM6());                        // tile t1 fully landed
        HALFGRP(1,
                STAGE(1, 0, 1, t2, BT, bn),    // B(t2)h1  -> buf0 B-kh1 (read P2)
                STAGE(1, 1, 0, t3, BT, bn),    // B(t3)h0  -> buf1 B-kh0 (read P4)
                STAGE(0, 1, 0, t3, A,  bm),    // A(t3)h0  -> buf1 A-kh0 (read P4,P5)
                STAGE(0, 1, 1, t3, A,  bm),    // A(t3)h1  -> buf1 A-kh1 (read P5,P6)
                VM6());                        // tile t2 fully landed
    }
    // ---- tail: tiles 30 (buf0), 31 (buf1); only B(31)h1 still to stage
    HALFGRP(0, STAGE(1, 1, 1, (KD / 64) - 1, BT, bn), , , , VM0());
    HALFGRP(1, , , , , );

    // ---- epilogue: D row = (lane>>4)*4 + r, col = l15 (m89 layout)
    const float sc = EPI ? scaling[0] : 0.f;
    const int r0 = (lane >> 4) * 4;
#pragma unroll
    for (int m = 0; m < 8; ++m) {
        const int grow0 = bm + wr * 128 + m * 16 + r0;
#pragma unroll
        for (int n = 0; n < 4; ++n) {
            const int gcol = bn + wc * 64 + n * 16 + l15;
            if constexpr (EPI) {
                const float bv = bias[gcol];
                float* o = (float*)Cout;
#pragma unroll
                for (int r = 0; r < 4; ++r)
                    o[(size_t)(grow0 + r) * ND + gcol] =
                        fmaxf(fmaf(sc, acc[m][n][r], bv), 0.f);
            } else {
                ushort* o = (ushort*)Cout;
#pragma unroll
                for (int r = 0; r < 4; ++r)
                    o[(size_t)(grow0 + r) * ND + gcol] = f2b(acc[m][n][r]);
            }
        }
    }
#undef STAGE
#undef HALFGRP
#undef MM4
#undef FA
#undef FB
}

extern "C" void kernel_launch(void* const* d_in, const int* in_sizes, int n_in,
                              void* d_out, int out_size, void* d_ws, size_t ws_size,
                              hipStream_t stream)
{
    // inputs: x, k0, k1, k2, m0, m1, m2, scaling, bias
    const float* x    = (const float*)d_in[0];
    const float* k0w  = (const float*)d_in[1];
    const float* k1w  = (const float*)d_in[2];
    const float* k2w  = (const float*)d_in[3];
    const float* m0w  = (const float*)d_in[4];
    const float* m1w  = (const float*)d_in[5];
    const float* m2w  = (const float*)d_in[6];
    const float* sc   = (const float*)d_in[7];
    const float* bias = (const float*)d_in[8];

    const int Md = in_sizes[0] / KD;               // 8192
    const size_t NE = (size_t)Md * KD;             // 16.7M elems

    // d_out (64MB fp32): [act1 bf16 32MB][x_bf16 32MB]; GEMM3 overwrites all.
    ushort* act1 = (ushort*)d_out;
    ushort* xb   = (ushort*)d_out + NE;
    float*  out  = (float*)d_out;
    // ws: [act2 bf16 32MB][wbT0 8MB][wbT1 8MB][wbT2 8MB] = 56MB
    ushort* act2 = (ushort*)d_ws;
    ushort* wbT  = (ushort*)d_ws + NE;

    dim3 bl(256);
    dim3 gX(NE / (256 * 8));                       // 8192
    dim3 gT(KD / 32, ND / 32, 3);                  // (64,64,3)
    dim3 gG(ND / 256, Md / 256), bG(512);          // (8,32) = 256 blocks, 1/CU

    convx <<<gX, bl, 0, stream>>>(x, xb);
    convT3<<<gT, bl, 0, stream>>>(k0w, k1w, k2w, m0w, m1w, m2w, wbT);

    gemm256<0><<<gG, bG, 0, stream>>>(xb,   wbT,                     act1, nullptr, nullptr);
    gemm256<0><<<gG, bG, 0, stream>>>(act1, wbT + (size_t)KD * ND,     act2, nullptr, nullptr);
    gemm256<1><<<gG, bG, 0, stream>>>(act2, wbT + (size_t)2 * KD * ND, out,  sc, bias);
}

// Round 6
// 224.922 us; speedup vs baseline: 11.0225x; 1.0451x over previous
//
#include <hip/hip_runtime.h>
#include <hip/hip_bf16.h>

// SparseFactorisationDense: out = relu(scaling * (x @ (k0*m0) @ (k1*m1) @ (k2*m2)) + bias)
// B=8192, D=U=2048.
// R6 = R5 + re-applied slot-XOR swizzle (T2). R5 dropped R4's swizzle on the
// wrong theory that 64B rows were naturally conflict-free; R4's zero conflicts
// were BECAUSE of the swizzle. 8-phase schedule unchanged from R5.
//   - physical 16B slot = logical ^ ((row>>1)&3), applied BOTH at the
//     global_load_lds SOURCE k-offset and at the fragment ds_read (rule #21)
//   - 256x256 tile, BK=64 as 2 k-halves, 512 thr / 8 waves (2Mx4N)
//   - counted vmcnt(6) at phases 4/8 only; raw s_barrier; setprio around MFMA

typedef __attribute__((ext_vector_type(8))) short  short8;
typedef __attribute__((ext_vector_type(8))) ushort ushort8v;
typedef __attribute__((ext_vector_type(4))) float  f32x4;

#define KD 2048
#define ND 2048

__device__ __forceinline__ ushort f2b(float f) {      // fp32 -> bf16 RNE
    union { float f; unsigned u; } v; v.f = f;
    unsigned r = v.u + 0x7fffu + ((v.u >> 16) & 1u);
    return (ushort)(r >> 16);
}

__device__ __forceinline__ void gload16(const ushort* g, ushort* l) {
    __builtin_amdgcn_global_load_lds(
        (const __attribute__((address_space(1))) void*)g,
        (__attribute__((address_space(3))) void*)l, 16, 0, 0);
}

// ---- x: fp32 -> bf16, 8 elems/thread
__global__ __launch_bounds__(256)
void convx(const float* __restrict__ x, ushort* __restrict__ xb)
{
    const size_t i = (size_t)blockIdx.x * 256 + threadIdx.x;
    const float4* src = reinterpret_cast<const float4*>(x) + i * 2;
    const float4 f0 = src[0], f1 = src[1];
    ushort8v u;
    u[0]=f2b(f0.x); u[1]=f2b(f0.y); u[2]=f2b(f0.z); u[3]=f2b(f0.w);
    u[4]=f2b(f1.x); u[5]=f2b(f1.y); u[6]=f2b(f1.z); u[7]=f2b(f1.w);
    reinterpret_cast<ushort8v*>(xb)[i] = u;
}

// ---- masked-weight transpose+convert for all 3 layers (blockIdx.z picks layer)
__global__ __launch_bounds__(256)
void convT3(const float* __restrict__ k0w, const float* __restrict__ k1w,
            const float* __restrict__ k2w, const float* __restrict__ m0w,
            const float* __restrict__ m1w, const float* __restrict__ m2w,
            ushort* __restrict__ wbT)
{
    const int z = blockIdx.z;
    const float* kw = z == 0 ? k0w : (z == 1 ? k1w : k2w);
    const float* mw = z == 0 ? m0w : (z == 1 ? m1w : m2w);
    ushort* o = wbT + (size_t)z * KD * ND;

    __shared__ ushort t[32][36];
    const int tid = threadIdx.x;
    const int bk = blockIdx.x * 32, bn = blockIdx.y * 32;
    {
        const int r = tid >> 3, c = (tid & 7) * 4;
        const size_t g = (size_t)(bk + r) * ND + bn + c;
        const float4 kv = *reinterpret_cast<const float4*>(kw + g);
        const float4 mv = *reinterpret_cast<const float4*>(mw + g);
        t[r][c + 0] = f2b(kv.x * mv.x);
        t[r][c + 1] = f2b(kv.y * mv.y);
        t[r][c + 2] = f2b(kv.z * mv.z);
        t[r][c + 3] = f2b(kv.w * mv.w);
    }
    __syncthreads();
    {
        const int n = tid >> 3, kq = (tid & 7) * 4;
        ushort4 ov;
        ov.x = t[kq + 0][n]; ov.y = t[kq + 1][n];
        ov.z = t[kq + 2][n]; ov.w = t[kq + 3][n];
        *reinterpret_cast<ushort4*>(&o[(size_t)(bn + n) * KD + bk + kq]) = ov;
    }
}

// ================= 256x256 8-phase GEMM =================
// C[M][N] = A[M][K] @ BT[N][K]^T, all bf16 in, fp32 accum.
template<int EPI>
__global__ __launch_bounds__(512, 2)
void gemm256(const ushort* __restrict__ A, const ushort* __restrict__ BT,
             void* __restrict__ Cout,
             const float* __restrict__ scaling, const float* __restrict__ bias)
{
    // [buf][op 0=A 1=B][kh][row*32 + k]  = 128 KiB
    __shared__ ushort S[2][2][2][256 * 32];

    const int tid  = threadIdx.x;
    const int lane = tid & 63;
    const int wid  = tid >> 6;                 // 0..7
    const int wr   = wid >> 2, wc = wid & 3;   // 2x4 wave grid: 128x64 per wave
    const int l15  = lane & 15;
    const int kq   = lane >> 4;                // fragment k-slot 0..3
    const int bn   = blockIdx.x * 256;
    const int bm   = blockIdx.y * 256;
    const int srow = lane >> 2;                // staging: 16 rows / gload
    const int wrow = wid * 32;                 // this wave's 32-row staging slice
    // both-sides involution: physical slot = logical slot ^ ((row>>1)&3)
    const int ssw  = ((lane & 3) ^ ((srow >> 1) & 3)) * 8;  // staged source k-off
    const int rsw  = (kq ^ ((l15 >> 1) & 3)) * 8;           // fragment read k-off

    f32x4 acc[8][4] = {};

#define STAGE(op, bufl, kh, tile, G, g0) do {                                        \
    gload16(G + (size_t)((g0) + wrow + srow)      * KD + (tile)*64 + (kh)*32 + ssw,  \
            &S[bufl][op][kh][(wrow)      * 32]);                                     \
    gload16(G + (size_t)((g0) + wrow + 16 + srow) * KD + (tile)*64 + (kh)*32 + ssw,  \
            &S[bufl][op][kh][(wrow + 16) * 32]);                                     \
  } while (0)

#define BAR()  asm volatile("s_barrier" ::: "memory")
#define VM6()  asm volatile("s_waitcnt vmcnt(6)" ::: "memory")
#define VM0()  asm volatile("s_waitcnt vmcnt(0)" ::: "memory")
#define LGK0() asm volatile("s_waitcnt lgkmcnt(0)" ::: "memory")
#define SB()   __builtin_amdgcn_sched_barrier(0)
#define PRI1() __builtin_amdgcn_s_setprio(1)
#define PRI0() __builtin_amdgcn_s_setprio(0)

#define FA(bufl, kh, m) (*(const short8*)&S[bufl][0][kh][(wr*128 + (m)*16 + l15)*32 + rsw])
#define FB(bufl, kh, n) (*(const short8*)&S[bufl][1][kh][(wc*64  + (n)*16 + l15)*32 + rsw])

#define MM4(r, av, b0_, b1_, b2_, b3_)                                                \
    acc[r][0] = __builtin_amdgcn_mfma_f32_16x16x32_bf16(av, b0_, acc[r][0], 0, 0, 0); \
    acc[r][1] = __builtin_amdgcn_mfma_f32_16x16x32_bf16(av, b1_, acc[r][1], 0, 0, 0); \
    acc[r][2] = __builtin_amdgcn_mfma_f32_16x16x32_bf16(av, b2_, acc[r][2], 0, 0, 0); \
    acc[r][3] = __builtin_amdgcn_mfma_f32_16x16x32_bf16(av, b3_, acc[r][3], 0, 0, 0)

// One K-tile = 4 phases. Reads: P0: A-kh0[0-3]+B-kh0; P1: A-kh0[4-7]+A-kh1[0-3];
// P2: A-kh1[4-7]+B-kh1; P3: none. Stage targets (ST0..ST3) are regions whose
// last read is a strictly earlier phase (per-phase end LGK0 enforces service).
#define HALFGRP(bufl, ST0, ST1, ST2, ST3, GATE) do {                                  \
    short8 xa0 = FA(bufl,0,0), xa1 = FA(bufl,0,1), xa2 = FA(bufl,0,2), xa3 = FA(bufl,0,3); \
    short8 xb0 = FB(bufl,0,0), xb1 = FB(bufl,0,1), xb2 = FB(bufl,0,2), xb3 = FB(bufl,0,3); \
    ST0; BAR(); SB(); PRI1();                                                         \
    MM4(0, xa0, xb0, xb1, xb2, xb3); MM4(1, xa1, xb0, xb1, xb2, xb3);                 \
    MM4(2, xa2, xb0, xb1, xb2, xb3); MM4(3, xa3, xb0, xb1, xb2, xb3);                 \
    PRI0(); SB(); LGK0(); BAR();                                                      \
    short8 xa4 = FA(bufl,0,4), xa5 = FA(bufl,0,5), xa6 = FA(bufl,0,6), xa7 = FA(bufl,0,7); \
    short8 xc0 = FA(bufl,1,0), xc1 = FA(bufl,1,1), xc2 = FA(bufl,1,2), xc3 = FA(bufl,1,3); \
    ST1; BAR(); SB(); PRI1();                                                         \
    MM4(4, xa4, xb0, xb1, xb2, xb3); MM4(5, xa5, xb0, xb1, xb2, xb3);                 \
    MM4(6, xa6, xb0, xb1, xb2, xb3); MM4(7, xa7, xb0, xb1, xb2, xb3);                 \
    PRI0(); SB(); LGK0(); BAR();                                                      \
    short8 xc4 = FA(bufl,1,4), xc5 = FA(bufl,1,5), xc6 = FA(bufl,1,6), xc7 = FA(bufl,1,7); \
    short8 xd0 = FB(bufl,1,0), xd1 = FB(bufl,1,1), xd2 = FB(bufl,1,2), xd3 = FB(bufl,1,3); \
    ST2; BAR(); SB(); PRI1();                                                         \
    MM4(0, xc0, xd0, xd1, xd2, xd3); MM4(1, xc1, xd0, xd1, xd2, xd3);                 \
    MM4(2, xc2, xd0, xd1, xd2, xd3); MM4(3, xc3, xd0, xd1, xd2, xd3);                 \
    PRI0(); SB(); LGK0(); BAR();                                                      \
    ST3; GATE; BAR(); SB(); PRI1();                                                   \
    MM4(4, xc4, xd0, xd1, xd2, xd3); MM4(5, xc5, xd0, xd1, xd2, xd3);                 \
    MM4(6, xc6, xd0, xd1, xd2, xd3); MM4(7, xc7, xd0, xd1, xd2, xd3);                 \
    PRI0(); SB(); LGK0(); BAR();                                                      \
  } while (0)

    // ---- prologue: tile0 (4 half-tiles) + tile1 (B-h0, A-h0, A-h1) = 7 stages
    STAGE(0, 0, 0, 0, A,  bm); STAGE(0, 0, 1, 0, A,  bm);
    STAGE(1, 0, 0, 0, BT, bn); STAGE(1, 0, 1, 0, BT, bn);
    STAGE(1, 1, 0, 1, BT, bn); STAGE(0, 1, 0, 1, A,  bm); STAGE(0, 1, 1, 1, A,  bm);
    VM6();   // drains tile 0's 8 loads; 3 half-tiles (tile 1) stay in flight
    BAR();

    const int NITER = KD / 128;                // 16
    for (int it = 0; it < NITER - 1; ++it) {
        const int t1 = 2 * it + 1, t2 = 2 * it + 2, t3 = 2 * it + 3;
        HALFGRP(0,
                STAGE(1, 1, 1, t1, BT, bn),    // B(t1)h1  -> buf1 B-kh1 (read prev iter)
                STAGE(1, 0, 0, t2, BT, bn),    // B(t2)h0  -> buf0 B-kh0 (read P0)
                STAGE(0, 0, 0, t2, A,  bm),    // A(t2)h0  -> buf0 A-kh0 (read P0,P1)
                STAGE(0, 0, 1, t2, A,  bm),    // A(t2)h1  -> buf0 A-kh1 (read P1,P2)
                VM6());                        // tile t1 fully landed
        HALFGRP(1,
                STAGE(1, 0, 1, t2, BT, bn),    // B(t2)h1  -> buf0 B-kh1 (read P2)
                STAGE(1, 1, 0, t3, BT, bn),    // B(t3)h0  -> buf1 B-kh0 (read P4)
                STAGE(0, 1, 0, t3, A,  bm),    // A(t3)h0  -> buf1 A-kh0 (read P4,P5)
                STAGE(0, 1, 1, t3, A,  bm),    // A(t3)h1  -> buf1 A-kh1 (read P5,P6)
                VM6());                        // tile t2 fully landed
    }
    // ---- tail: tiles 30 (buf0), 31 (buf1); only B(31)h1 still to stage
    HALFGRP(0, STAGE(1, 1, 1, (KD / 64) - 1, BT, bn), , , , VM0());
    HALFGRP(1, , , , , );

    // ---- epilogue: D row = (lane>>4)*4 + r, col = l15 (m89 layout)
    const float sc = EPI ? scaling[0] : 0.f;
    const int r0 = (lane >> 4) * 4;
#pragma unroll
    for (int m = 0; m < 8; ++m) {
        const int grow0 = bm + wr * 128 + m * 16 + r0;
#pragma unroll
        for (int n = 0; n < 4; ++n) {
            const int gcol = bn + wc * 64 + n * 16 + l15;
            if constexpr (EPI) {
                const float bv = bias[gcol];
                float* o = (float*)Cout;
#pragma unroll
                for (int r = 0; r < 4; ++r)
                    o[(size_t)(grow0 + r) * ND + gcol] =
                        fmaxf(fmaf(sc, acc[m][n][r], bv), 0.f);
            } else {
                ushort* o = (ushort*)Cout;
#pragma unroll
                for (int r = 0; r < 4; ++r)
                    o[(size_t)(grow0 + r) * ND + gcol] = f2b(acc[m][n][r]);
            }
        }
    }
#undef STAGE
#undef HALFGRP
#undef MM4
#undef FA
#undef FB
}

extern "C" void kernel_launch(void* const* d_in, const int* in_sizes, int n_in,
                              void* d_out, int out_size, void* d_ws, size_t ws_size,
                              hipStream_t stream)
{
    // inputs: x, k0, k1, k2, m0, m1, m2, scaling, bias
    const float* x    = (const float*)d_in[0];
    const float* k0w  = (const float*)d_in[1];
    const float* k1w  = (const float*)d_in[2];
    const float* k2w  = (const float*)d_in[3];
    const float* m0w  = (const float*)d_in[4];
    const float* m1w  = (const float*)d_in[5];
    const float* m2w  = (const float*)d_in[6];
    const float* sc   = (const float*)d_in[7];
    const float* bias = (const float*)d_in[8];

    const int Md = in_sizes[0] / KD;               // 8192
    const size_t NE = (size_t)Md * KD;             // 16.7M elems

    // d_out (64MB fp32): [act1 bf16 32MB][x_bf16 32MB]; GEMM3 overwrites all.
    ushort* act1 = (ushort*)d_out;
    ushort* xb   = (ushort*)d_out + NE;
    float*  out  = (float*)d_out;
    // ws: [act2 bf16 32MB][wbT0 8MB][wbT1 8MB][wbT2 8MB] = 56MB
    ushort* act2 = (ushort*)d_ws;
    ushort* wbT  = (ushort*)d_ws + NE;

    dim3 bl(256);
    dim3 gX(NE / (256 * 8));                       // 8192
    dim3 gT(KD / 32, ND / 32, 3);                  // (64,64,3)
    dim3 gG(ND / 256, Md / 256), bG(512);          // (8,32) = 256 blocks, 1/CU

    convx <<<gX, bl, 0, stream>>>(x, xb);
    convT3<<<gT, bl, 0, stream>>>(k0w, k1w, k2w, m0w, m1w, m2w, wbT);

    gemm256<0><<<gG, bG, 0, stream>>>(xb,   wbT,                     act1, nullptr, nullptr);
    gemm256<0><<<gG, bG, 0, stream>>>(act1, wbT + (size_t)KD * ND,     act2, nullptr, nullptr);
    gemm256<1><<<gG, bG, 0, stream>>>(act2, wbT + (size_t)2 * KD * ND, out,  sc, bias);
}

// Round 7
// 218.713 us; speedup vs baseline: 11.3354x; 1.0284x over previous
//
#include <hip/hip_runtime.h>
#include <hip/hip_bf16.h>

// SparseFactorisationDense: out = relu(scaling * (x @ (k0*m0) @ (k1*m1) @ (k2*m2)) + bias)
// B=8192, D=U=2048.
// R7 = R6 + (T1) bijective XCD-aware block swizzle + operand-swapped MFMA for
// packed epilogue stores.
//   - T1: tile_id = (wgid%8)*32 + wgid/8  (256 blocks, 8 XCDs -> each XCD gets
//     a contiguous 8bx x 4by chunk; per-K-slice L2 working set ~384 KB)
//   - mfma(bf, af): D row=n col=m, lane holds 4 consecutive n in acc regs ->
//     ushort4 (bf16) / float4 (fp32) epilogue stores instead of 2B scatter
//   - 8-phase schedule, slot-XOR swizzle, vmcnt(6) gates: identical to R6

typedef __attribute__((ext_vector_type(8))) short  short8;
typedef __attribute__((ext_vector_type(8))) ushort ushort8v;
typedef __attribute__((ext_vector_type(4))) float  f32x4;

#define KD 2048
#define ND 2048

__device__ __forceinline__ ushort f2b(float f) {      // fp32 -> bf16 RNE
    union { float f; unsigned u; } v; v.f = f;
    unsigned r = v.u + 0x7fffu + ((v.u >> 16) & 1u);
    return (ushort)(r >> 16);
}

__device__ __forceinline__ void gload16(const ushort* g, ushort* l) {
    __builtin_amdgcn_global_load_lds(
        (const __attribute__((address_space(1))) void*)g,
        (__attribute__((address_space(3))) void*)l, 16, 0, 0);
}

// ---- x: fp32 -> bf16, 8 elems/thread
__global__ __launch_bounds__(256)
void convx(const float* __restrict__ x, ushort* __restrict__ xb)
{
    const size_t i = (size_t)blockIdx.x * 256 + threadIdx.x;
    const float4* src = reinterpret_cast<const float4*>(x) + i * 2;
    const float4 f0 = src[0], f1 = src[1];
    ushort8v u;
    u[0]=f2b(f0.x); u[1]=f2b(f0.y); u[2]=f2b(f0.z); u[3]=f2b(f0.w);
    u[4]=f2b(f1.x); u[5]=f2b(f1.y); u[6]=f2b(f1.z); u[7]=f2b(f1.w);
    reinterpret_cast<ushort8v*>(xb)[i] = u;
}

// ---- masked-weight transpose+convert for all 3 layers (blockIdx.z picks layer)
__global__ __launch_bounds__(256)
void convT3(const float* __restrict__ k0w, const float* __restrict__ k1w,
            const float* __restrict__ k2w, const float* __restrict__ m0w,
            const float* __restrict__ m1w, const float* __restrict__ m2w,
            ushort* __restrict__ wbT)
{
    const int z = blockIdx.z;
    const float* kw = z == 0 ? k0w : (z == 1 ? k1w : k2w);
    const float* mw = z == 0 ? m0w : (z == 1 ? m1w : m2w);
    ushort* o = wbT + (size_t)z * KD * ND;

    __shared__ ushort t[32][36];
    const int tid = threadIdx.x;
    const int bk = blockIdx.x * 32, bn = blockIdx.y * 32;
    {
        const int r = tid >> 3, c = (tid & 7) * 4;
        const size_t g = (size_t)(bk + r) * ND + bn + c;
        const float4 kv = *reinterpret_cast<const float4*>(kw + g);
        const float4 mv = *reinterpret_cast<const float4*>(mw + g);
        t[r][c + 0] = f2b(kv.x * mv.x);
        t[r][c + 1] = f2b(kv.y * mv.y);
        t[r][c + 2] = f2b(kv.z * mv.z);
        t[r][c + 3] = f2b(kv.w * mv.w);
    }
    __syncthreads();
    {
        const int n = tid >> 3, kq = (tid & 7) * 4;
        ushort4 ov;
        ov.x = t[kq + 0][n]; ov.y = t[kq + 1][n];
        ov.z = t[kq + 2][n]; ov.w = t[kq + 3][n];
        *reinterpret_cast<ushort4*>(&o[(size_t)(bn + n) * KD + bk + kq]) = ov;
    }
}

// ================= 256x256 8-phase GEMM =================
// C[M][N] = A[M][K] @ BT[N][K]^T, all bf16 in, fp32 accum.
template<int EPI>
__global__ __launch_bounds__(512, 2)
void gemm256(const ushort* __restrict__ A, const ushort* __restrict__ BT,
             void* __restrict__ Cout,
             const float* __restrict__ scaling, const float* __restrict__ bias)
{
    // [buf][op 0=A 1=B][kh][row*32 + k]  = 128 KiB
    __shared__ ushort S[2][2][2][256 * 32];

    const int tid  = threadIdx.x;
    const int lane = tid & 63;
    const int wid  = tid >> 6;                 // 0..7
    const int wr   = wid >> 2, wc = wid & 3;   // 2x4 wave grid: 128x64 per wave
    const int l15  = lane & 15;
    const int kq   = lane >> 4;                // fragment k-slot 0..3
    // T1: bijective XCD swizzle (256 blocks % 8 XCDs == 0)
    const int id   = blockIdx.x;
    const int swz  = (id & 7) * 32 + (id >> 3);
    const int bn   = (swz & 7) * 256;          // 8 N-blocks
    const int bm   = (swz >> 3) * 256;         // 32 M-blocks
    const int srow = lane >> 2;                // staging: 16 rows / gload
    const int wrow = wid * 32;                 // this wave's 32-row staging slice
    // both-sides involution: physical slot = logical slot ^ ((row>>1)&3)
    const int ssw  = ((lane & 3) ^ ((srow >> 1) & 3)) * 8;  // staged source k-off
    const int rsw  = (kq ^ ((l15 >> 1) & 3)) * 8;           // fragment read k-off

    f32x4 acc[8][4] = {};

#define STAGE(op, bufl, kh, tile, G, g0) do {                                        \
    gload16(G + (size_t)((g0) + wrow + srow)      * KD + (tile)*64 + (kh)*32 + ssw,  \
            &S[bufl][op][kh][(wrow)      * 32]);                                     \
    gload16(G + (size_t)((g0) + wrow + 16 + srow) * KD + (tile)*64 + (kh)*32 + ssw,  \
            &S[bufl][op][kh][(wrow + 16) * 32]);                                     \
  } while (0)

#define BAR()  asm volatile("s_barrier" ::: "memory")
#define VM6()  asm volatile("s_waitcnt vmcnt(6)" ::: "memory")
#define VM0()  asm volatile("s_waitcnt vmcnt(0)" ::: "memory")
#define LGK0() asm volatile("s_waitcnt lgkmcnt(0)" ::: "memory")
#define SB()   __builtin_amdgcn_sched_barrier(0)
#define PRI1() __builtin_amdgcn_s_setprio(1)
#define PRI0() __builtin_amdgcn_s_setprio(0)

#define FA(bufl, kh, m) (*(const short8*)&S[bufl][0][kh][(wr*128 + (m)*16 + l15)*32 + rsw])
#define FB(bufl, kh, n) (*(const short8*)&S[bufl][1][kh][(wc*64  + (n)*16 + l15)*32 + rsw])

// operand-swapped: D row = n (lane's 4 consecutive in regs), col = m (l15)
#define MM4(r, av, b0_, b1_, b2_, b3_)                                                \
    acc[r][0] = __builtin_amdgcn_mfma_f32_16x16x32_bf16(b0_, av, acc[r][0], 0, 0, 0); \
    acc[r][1] = __builtin_amdgcn_mfma_f32_16x16x32_bf16(b1_, av, acc[r][1], 0, 0, 0); \
    acc[r][2] = __builtin_amdgcn_mfma_f32_16x16x32_bf16(b2_, av, acc[r][2], 0, 0, 0); \
    acc[r][3] = __builtin_amdgcn_mfma_f32_16x16x32_bf16(b3_, av, acc[r][3], 0, 0, 0)

// One K-tile = 4 phases. Reads: P0: A-kh0[0-3]+B-kh0; P1: A-kh0[4-7]+A-kh1[0-3];
// P2: A-kh1[4-7]+B-kh1; P3: none. Stage targets (ST0..ST3) are regions whose
// last read is a strictly earlier phase (per-phase end LGK0 enforces service).
#define HALFGRP(bufl, ST0, ST1, ST2, ST3, GATE) do {                                  \
    short8 xa0 = FA(bufl,0,0), xa1 = FA(bufl,0,1), xa2 = FA(bufl,0,2), xa3 = FA(bufl,0,3); \
    short8 xb0 = FB(bufl,0,0), xb1 = FB(bufl,0,1), xb2 = FB(bufl,0,2), xb3 = FB(bufl,0,3); \
    ST0; BAR(); SB(); PRI1();                                                         \
    MM4(0, xa0, xb0, xb1, xb2, xb3); MM4(1, xa1, xb0, xb1, xb2, xb3);                 \
    MM4(2, xa2, xb0, xb1, xb2, xb3); MM4(3, xa3, xb0, xb1, xb2, xb3);                 \
    PRI0(); SB(); LGK0(); BAR();                                                      \
    short8 xa4 = FA(bufl,0,4), xa5 = FA(bufl,0,5), xa6 = FA(bufl,0,6), xa7 = FA(bufl,0,7); \
    short8 xc0 = FA(bufl,1,0), xc1 = FA(bufl,1,1), xc2 = FA(bufl,1,2), xc3 = FA(bufl,1,3); \
    ST1; BAR(); SB(); PRI1();                                                         \
    MM4(4, xa4, xb0, xb1, xb2, xb3); MM4(5, xa5, xb0, xb1, xb2, xb3);                 \
    MM4(6, xa6, xb0, xb1, xb2, xb3); MM4(7, xa7, xb0, xb1, xb2, xb3);                 \
    PRI0(); SB(); LGK0(); BAR();                                                      \
    short8 xc4 = FA(bufl,1,4), xc5 = FA(bufl,1,5), xc6 = FA(bufl,1,6), xc7 = FA(bufl,1,7); \
    short8 xd0 = FB(bufl,1,0), xd1 = FB(bufl,1,1), xd2 = FB(bufl,1,2), xd3 = FB(bufl,1,3); \
    ST2; BAR(); SB(); PRI1();                                                         \
    MM4(0, xc0, xd0, xd1, xd2, xd3); MM4(1, xc1, xd0, xd1, xd2, xd3);                 \
    MM4(2, xc2, xd0, xd1, xd2, xd3); MM4(3, xc3, xd0, xd1, xd2, xd3);                 \
    PRI0(); SB(); LGK0(); BAR();                                                      \
    ST3; GATE; BAR(); SB(); PRI1();                                                   \
    MM4(4, xc4, xd0, xd1, xd2, xd3); MM4(5, xc5, xd0, xd1, xd2, xd3);                 \
    MM4(6, xc6, xd0, xd1, xd2, xd3); MM4(7, xc7, xd0, xd1, xd2, xd3);                 \
    PRI0(); SB(); LGK0(); BAR();                                                      \
  } while (0)

    // ---- prologue: tile0 (4 half-tiles) + tile1 (B-h0, A-h0, A-h1) = 7 stages
    STAGE(0, 0, 0, 0, A,  bm); STAGE(0, 0, 1, 0, A,  bm);
    STAGE(1, 0, 0, 0, BT, bn); STAGE(1, 0, 1, 0, BT, bn);
    STAGE(1, 1, 0, 1, BT, bn); STAGE(0, 1, 0, 1, A,  bm); STAGE(0, 1, 1, 1, A,  bm);
    VM6();   // drains tile 0's 8 loads; 3 half-tiles (tile 1) stay in flight
    BAR();

    const int NITER = KD / 128;                // 16
    for (int it = 0; it < NITER - 1; ++it) {
        const int t1 = 2 * it + 1, t2 = 2 * it + 2, t3 = 2 * it + 3;
        HALFGRP(0,
                STAGE(1, 1, 1, t1, BT, bn),    // B(t1)h1  -> buf1 B-kh1 (read prev iter)
                STAGE(1, 0, 0, t2, BT, bn),    // B(t2)h0  -> buf0 B-kh0 (read P0)
                STAGE(0, 0, 0, t2, A,  bm),    // A(t2)h0  -> buf0 A-kh0 (read P0,P1)
                STAGE(0, 0, 1, t2, A,  bm),    // A(t2)h1  -> buf0 A-kh1 (read P1,P2)
                VM6());                        // tile t1 fully landed
        HALFGRP(1,
                STAGE(1, 0, 1, t2, BT, bn),    // B(t2)h1  -> buf0 B-kh1 (read P2)
                STAGE(1, 1, 0, t3, BT, bn),    // B(t3)h0  -> buf1 B-kh0 (read P4)
                STAGE(0, 1, 0, t3, A,  bm),    // A(t3)h0  -> buf1 A-kh0 (read P4,P5)
                STAGE(0, 1, 1, t3, A,  bm),    // A(t3)h1  -> buf1 A-kh1 (read P5,P6)
                VM6());                        // tile t2 fully landed
    }
    // ---- tail: tiles 30 (buf0), 31 (buf1); only B(31)h1 still to stage
    HALFGRP(0, STAGE(1, 1, 1, (KD / 64) - 1, BT, bn), , , , VM0());
    HALFGRP(1, , , , , );

    // ---- epilogue (swapped layout): lane covers row m = l15, cols n0+0..3
    const float sc = EPI ? scaling[0] : 0.f;
#pragma unroll
    for (int m = 0; m < 8; ++m) {
        const size_t grow = (size_t)(bm + wr * 128 + m * 16 + l15);
#pragma unroll
        for (int n = 0; n < 4; ++n) {
            const int gcol = bn + wc * 64 + n * 16 + kq * 4;
            if constexpr (EPI) {
                const float4 bv = *reinterpret_cast<const float4*>(bias + gcol);
                float4 v;
                v.x = fmaxf(fmaf(sc, acc[m][n][0], bv.x), 0.f);
                v.y = fmaxf(fmaf(sc, acc[m][n][1], bv.y), 0.f);
                v.z = fmaxf(fmaf(sc, acc[m][n][2], bv.z), 0.f);
                v.w = fmaxf(fmaf(sc, acc[m][n][3], bv.w), 0.f);
                *reinterpret_cast<float4*>((float*)Cout + grow * ND + gcol) = v;
            } else {
                ushort4 v;
                v.x = f2b(acc[m][n][0]); v.y = f2b(acc[m][n][1]);
                v.z = f2b(acc[m][n][2]); v.w = f2b(acc[m][n][3]);
                *reinterpret_cast<ushort4*>((ushort*)Cout + grow * ND + gcol) = v;
            }
        }
    }
#undef STAGE
#undef HALFGRP
#undef MM4
#undef FA
#undef FB
}

extern "C" void kernel_launch(void* const* d_in, const int* in_sizes, int n_in,
                              void* d_out, int out_size, void* d_ws, size_t ws_size,
                              hipStream_t stream)
{
    // inputs: x, k0, k1, k2, m0, m1, m2, scaling, bias
    const float* x    = (const float*)d_in[0];
    const float* k0w  = (const float*)d_in[1];
    const float* k1w  = (const float*)d_in[2];
    const float* k2w  = (const float*)d_in[3];
    const float* m0w  = (const float*)d_in[4];
    const float* m1w  = (const float*)d_in[5];
    const float* m2w  = (const float*)d_in[6];
    const float* sc   = (const float*)d_in[7];
    const float* bias = (const float*)d_in[8];

    const int Md = in_sizes[0] / KD;               // 8192
    const size_t NE = (size_t)Md * KD;             // 16.7M elems

    // d_out (64MB fp32): [act1 bf16 32MB][x_bf16 32MB]; GEMM3 overwrites all.
    ushort* act1 = (ushort*)d_out;
    ushort* xb   = (ushort*)d_out + NE;
    float*  out  = (float*)d_out;
    // ws: [act2 bf16 32MB][wbT0 8MB][wbT1 8MB][wbT2 8MB] = 56MB
    ushort* act2 = (ushort*)d_ws;
    ushort* wbT  = (ushort*)d_ws + NE;

    dim3 bl(256);
    dim3 gX(NE / (256 * 8));                       // 8192
    dim3 gT(KD / 32, ND / 32, 3);                  // (64,64,3)
    dim3 gG((ND / 256) * (Md / 256)), bG(512);     // 256 blocks 1D (XCD swizzle inside)

    convx <<<gX, bl, 0, stream>>>(x, xb);
    convT3<<<gT, bl, 0, stream>>>(k0w, k1w, k2w, m0w, m1w, m2w, wbT);

    gemm256<0><<<gG, bG, 0, stream>>>(xb,   wbT,                     act1, nullptr, nullptr);
    gemm256<0><<<gG, bG, 0, stream>>>(act1, wbT + (size_t)KD * ND,     act2, nullptr, nullptr);
    gemm256<1><<<gG, bG, 0, stream>>>(act2, wbT + (size_t)2 * KD * ND, out,  sc, bias);
}